// Round 17
// baseline (3289.013 us; speedup 1.0000x reference)
//
#include <hip/hip_runtime.h>
#include <stdint.h>

#define DD 128
#define NJ 25000
#define NI 12500

__device__ __forceinline__ uint32_t rotl32(uint32_t v, int n) {
  return (v << n) | (v >> (32 - n));
}

// JAX threefry2x32, key=(0,1). Core KAT-verified vs Random123.
__device__ __forceinline__ void threefry_0_1(uint32_t& x0, uint32_t& x1) {
  const uint32_t ks0 = 0u, ks1 = 1u, ks2 = 0x1BD11BDBu;
  x0 += ks0; x1 += ks1;
#define TF_R4(a,b,c,d)                                  \
  x0 += x1; x1 = rotl32(x1,(a)); x1 ^= x0;              \
  x0 += x1; x1 = rotl32(x1,(b)); x1 ^= x0;              \
  x0 += x1; x1 = rotl32(x1,(c)); x1 ^= x0;              \
  x0 += x1; x1 = rotl32(x1,(d)); x1 ^= x0;
  TF_R4(13,15,26,6)   x0 += ks1; x1 += ks2 + 1u;
  TF_R4(17,29,16,24)  x0 += ks2; x1 += ks0 + 2u;
  TF_R4(13,15,26,6)   x0 += ks0; x1 += ks1 + 3u;
  TF_R4(17,29,16,24)  x0 += ks1; x1 += ks2 + 4u;
  TF_R4(13,15,26,6)   x0 += ks2; x1 += ks0 + 5u;
#undef TF_R4
}

// MASK IDENTIFIED (R16 sweep, unique match v5): partitionable threefry,
// ctr = (0, f), 32-bit draw = o0 ^ o1; keep <=> bit31(o0 ^ o1) == 0.
__device__ __forceinline__ bool dropout_keep(uint32_t f) {
  uint32_t x0 = 0u, x1 = f;
  threefry_0_1(x0, x1);
  return ((x0 ^ x1) >> 31) == 0u;
}

// int64-as-int32-pairs detection (odd words all zero for values < 2^31).
__global__ void detect_i64(const int* __restrict__ w, int* __restrict__ flag) {
  if (threadIdx.x == 0 && blockIdx.x == 0) {
    int is64 = 1;
    for (int e = 0; e < 16; ++e)
      if (w[2 * e + 1] != 0) is64 = 0;
    *flag = is64;
  }
}

// WTp[(k>>2)*512 + c*4 + (k&3)] = Wcat[c][k]; Wcat = [W_l | W_r] along k.
__global__ void prep_wt(const float* __restrict__ Wl,
                        const float* __restrict__ Wr,
                        float* __restrict__ WTp) {
  int idx = blockIdx.x * blockDim.x + threadIdx.x;  // idx = c*256 + k
  if (idx >= DD * 256) return;
  int c = idx >> 8;
  int k = idx & 255;
  float v = (k < DD) ? Wl[c * DD + k] : Wr[c * DD + (k - DD)];
  WTp[(k >> 2) * (DD * 4) + c * 4 + (k & 3)] = v;
}

// Edge-parallel scatter: agg[dst] += x[src], deg[dst] += 1 (dst < dstLimit).
// 4 threads/edge, float4 lanes.
__global__ void scatter_kernel(const int* __restrict__ adj,
                               const float* __restrict__ x,
                               float* __restrict__ agg,
                               float* __restrict__ deg,
                               const int* __restrict__ flagIdx,
                               int nE, int dstLimit) {
  int t = blockIdx.x * blockDim.x + threadIdx.x;
  int e = t >> 2;
  int p = t & 3;
  if (e >= nE) return;
  int s, d;
  if (*flagIdx) {
    s = adj[2 * e];
    d = adj[2 * nE + 2 * e];
  } else {
    s = adj[e];
    d = adj[nE + e];
  }
  if (d >= dstLimit) return;
  const float4* xr = (const float4*)(x + (size_t)s * DD) + p * 8;
  float* ar = agg + (size_t)d * DD + p * 32;
  if (p == 0) unsafeAtomicAdd(&deg[d], 1.0f);
#pragma unroll
  for (int q = 0; q < 8; ++q) {
    float4 v = xr[q];
    unsafeAtomicAdd(ar + q * 4 + 0, v.x);
    unsafeAtomicAdd(ar + q * 4 + 1, v.y);
    unsafeAtomicAdd(ar + q * 4 + 2, v.z);
    unsafeAtomicAdd(ar + q * 4 + 3, v.w);
  }
}

// Tiled dense: out[r][c] = bias[c] + sum_k [agg/deg || xin][k] * Wcat[c][k].
// 8 rows/block, fp32 throughout. LAYER==1: relu+dropout (x1 may ALIAS agg:
// each block reads only its rows before __syncthreads, writes after).
template <int LAYER>
__global__ __launch_bounds__(256) void dense_kernel(
    const float* __restrict__ agg, const float* __restrict__ deg,
    const float* __restrict__ xin, const float* __restrict__ WTp,
    const float* __restrict__ bias, float* __restrict__ out, int M) {
  __shared__ float As[8 * 256];
  const int tid = threadIdx.x;
  const int c = tid & 127;
  const int rh = tid >> 7;
  const int rowBase = blockIdx.x * 8;

#pragma unroll
  for (int base = 0; base < 2048; base += 1024) {
    int f = base + tid * 4;
    int r = f >> 8;
    int k = f & 255;
    int rg = rowBase + r;
    if (rg >= M) rg = M - 1;  // clamped read; stores guarded below
    float4 v;
    if (k < DD) {
      float rdeg = 1.0f / fmaxf(deg[rg], 1.0f);
      v = *(const float4*)(agg + (size_t)rg * DD + k);
      v.x *= rdeg; v.y *= rdeg; v.z *= rdeg; v.w *= rdeg;
    } else {
      v = *(const float4*)(xin + (size_t)rg * DD + (k - DD));
    }
    *(float4*)(As + f) = v;
  }
  __syncthreads();

  float acc[4] = {0.f, 0.f, 0.f, 0.f};
  const int r0 = rh * 4;
#pragma unroll 8
  for (int k0 = 0; k0 < 256; k0 += 4) {
    float4 w = *(const float4*)(WTp + (k0 >> 2) * (DD * 4) + c * 4);
#pragma unroll
    for (int r = 0; r < 4; ++r) {
      float4 a = *(const float4*)(As + (r0 + r) * 256 + k0);
      acc[r] += a.x * w.x + a.y * w.y + a.z * w.z + a.w * w.w;
    }
  }

  float b = bias[c];
#pragma unroll
  for (int r = 0; r < 4; ++r) {
    int rg = rowBase + r0 + r;
    if (rg >= M) continue;
    float v = acc[r] + b;
    if (LAYER == 1) {
      v = fmaxf(v, 0.0f);
      uint32_t f = (uint32_t)rg * DD + (uint32_t)c;
      v = dropout_keep(f) ? v * 2.0f : 0.0f;
    }
    out[(size_t)rg * DD + c] = v;
  }
}

extern "C" void kernel_launch(void* const* d_in, const int* in_sizes, int n_in,
                              void* d_out, int out_size, void* d_ws, size_t ws_size,
                              hipStream_t stream) {
  const float* feat = (const float*)d_in[0];   // fp32 (R4 NaN proof)
  const int* t_adj = (const int*)d_in[1];
  const int* n_adj = (const int*)d_in[2];
  const float* W1l = (const float*)d_in[5];
  const float* b1 = (const float*)d_in[6];
  const float* W1r = (const float*)d_in[7];
  const float* W2l = (const float*)d_in[8];
  const float* b2 = (const float*)d_in[9];
  const float* W2r = (const float*)d_in[10];

  const int E1 = in_sizes[1] / 2;
  const int E2 = in_sizes[2] / 2;

  // Workspace ~19.6 MB. x1 aliases agg1 (race-free; see dense_kernel note).
  float* ws = (float*)d_ws;
  float* agg1 = ws;                     // 3,200,000 f (also x1)
  float* x1 = agg1;                     // alias
  float* agg2 = agg1 + 3200000;         // 1,600,000 f
  float* deg1 = agg2 + 1600000;         //    25,000 f
  float* deg2 = deg1 + 25000;           //    12,500 f
  float* WT1 = deg2 + 12500;            //    32,768 f
  float* WT2 = WT1 + 32768;             //    32,768 f
  int* flagIdx = (int*)(WT2 + 32768);   //         1

  hipMemsetAsync(d_ws, 0,
                 (size_t)(3200000 + 1600000 + 25000 + 12500) * sizeof(float),
                 stream);

  detect_i64<<<1, 64, 0, stream>>>(t_adj, flagIdx);

  prep_wt<<<(DD * 256 + 255) / 256, 256, 0, stream>>>(W1l, W1r, WT1);
  prep_wt<<<(DD * 256 + 255) / 256, 256, 0, stream>>>(W2l, W2r, WT2);

  scatter_kernel<<<(E1 * 4 + 255) / 256, 256, 0, stream>>>(
      t_adj, feat, agg1, deg1, flagIdx, E1, NJ);

  dense_kernel<1><<<(NJ + 7) / 8, 256, 0, stream>>>(agg1, deg1, feat, WT1, b1,
                                                    x1, NJ);

  scatter_kernel<<<(E2 * 4 + 255) / 256, 256, 0, stream>>>(
      n_adj, x1, agg2, deg2, flagIdx, E2, NI);

  dense_kernel<2><<<(NI + 7) / 8, 256, 0, stream>>>(agg2, deg2, x1, WT2, b2,
                                                    (float*)d_out, NI);
}